// Round 5
// baseline (155.714 us; speedup 1.0000x reference)
//
#include <hip/hip_runtime.h>
#include <math.h>

// SIREN forward: coords [N,3] -> first(3->5,sin) -> 256 x hidden(5->5,sin) -> final(5->1)
// Output layout: d_out[0..N) = net output, d_out[N..4N) = coords passthrough.
//
// Round 5:
//  - Replace v_sin_f32 with a full-rate polynomial. Cross-round counter fit
//    showed v_sin_f32 costs ~19-20 VALU-busy cyc/wave64, invariant to TLP and
//    ILP (hard trans-unit serialization) -> sins were ~60% of busy cycles.
//    Poly = rndne+sub+mul+4fma+mul = 8 full-rate instrs (16 cyc, pipelined).
//  - Degree-9 odd Chebyshev poly for sin(2*pi*r), r in [-0.5,0.5] (coeffs from
//    Bessel expansion, verified: max abs err ~3e-5/sin; random-walk over 256
//    layers ~5e-4 << 2e-2 threshold).
//  - Weights pre-scaled by 30/(2pi) in d_ws ([256][32] f32): args stay in
//    revolution units, |z| <= ~7.6 rev, rndne reduction exact.
//  - 4 points/thread (20 independent sin chains), uniform CF, scalar weights.

#define SIREN_HID 5
#define SIREN_NLAYERS 256
// 30 / (2*pi)
#define SIREN_REV 4.774648292756860f
#define PTS 4

// sin(2*pi*z) via degree-9 odd Chebyshev-truncated poly after exact range
// reduction. All full-rate VALU ops.
__device__ __forceinline__ float sinrev(float z) {
    float k  = __builtin_rintf(z);        // v_rndne_f32
    float r  = z - k;                      // exact, r in [-0.5, 0.5]
    float r2 = r * r;
    float p  = fmaf(32.768f,       r2, -74.4734720f);
    p        = fmaf(p,             r2,  81.3648896f);
    p        = fmaf(p,             r2, -41.3310592f);
    p        = fmaf(p,             r2,   6.2830548f);
    return p * r;
}

// ---------------- prep: scale weights into revolution units ----------------
// d_ws layout (floats):
//   [0 .. 8192)        hidden layers: layer l at l*32: w[0..24], b[25..29], pad
//   [8192 .. 8207)     first layer W (5x3, row-major), scaled
//   [8207 .. 8212)     first layer b, scaled
__global__ __launch_bounds__(256)
void siren_prep(const float* __restrict__ Wf, const float* __restrict__ bf,
                const float* __restrict__ Wh, const float* __restrict__ bh,
                float* __restrict__ ws)
{
    int t = blockIdx.x * blockDim.x + threadIdx.x;
    const int total = SIREN_NLAYERS * 32;
    for (int idx = t; idx < total; idx += gridDim.x * blockDim.x) {
        int l = idx >> 5;
        int k = idx & 31;
        float v = 0.0f;
        if (k < 25)      v = Wh[l * 25 + k] * SIREN_REV;
        else if (k < 30) v = bh[l * 5 + (k - 25)] * SIREN_REV;
        ws[idx] = v;
    }
    if (t < 15) ws[total + t]      = Wf[t] * SIREN_REV;
    if (t < 5)  ws[total + 15 + t] = bf[t] * SIREN_REV;
}

// ---------------- main: 4 points per thread, poly sin ----------------
__global__ __launch_bounds__(256)
void siren_fwd5(const float* __restrict__ coords,
                const float* __restrict__ lw,    // [256][32] scaled hidden w/b
                const float* __restrict__ fw,    // [20] scaled first w(15)+b(5)
                const float* __restrict__ Wfin,  // [1][5] (unscaled)
                const float* __restrict__ bfin,  // [1]
                float* __restrict__ out, int N)
{
    int i = blockIdx.x * blockDim.x + threadIdx.x;
    const int M = N / PTS;                // groups of 4 points
    i = (i < M) ? i : (M - 1);            // uniform clamp, no divergent return

    // 4 adjacent points: 48B contiguous load as 3x float4
    const float4* cp4 = (const float4*)(coords + 3 * PTS * i);
    float4 q0 = cp4[0];   // a0 a1 a2 b0
    float4 q1 = cp4[1];   // b1 b2 c0 c1
    float4 q2 = cp4[2];   // c2 d0 d1 d2
    float c[PTS][3] = {
        { q0.x, q0.y, q0.z },
        { q0.w, q1.x, q1.y },
        { q1.z, q1.w, q2.x },
        { q2.y, q2.z, q2.w },
    };

    float h[PTS][SIREN_HID];

    // first layer (revolution units): h_j = sin_rev(c . w[j,:] + b[j])
    {
#pragma unroll
        for (int p = 0; p < PTS; ++p) {
#pragma unroll
            for (int j = 0; j < SIREN_HID; ++j) {
                float z = fmaf(c[p][2], fw[3 * j + 2],
                          fmaf(c[p][1], fw[3 * j + 1],
                          fmaf(c[p][0], fw[3 * j + 0], fw[15 + j])));
                h[p][j] = sinrev(z);
            }
        }
    }

    // 256 hidden layers (revolution units)
#pragma unroll 2
    for (int l = 0; l < SIREN_NLAYERS; ++l) {
        const float* w = lw + l * 32;
        // biases: one v_mov each, shared by all 4 points' chains
        float b0 = w[25], b1 = w[26], b2 = w[27], b3 = w[28], b4 = w[29];
        float z[PTS][SIREN_HID];
#pragma unroll
        for (int p = 0; p < PTS; ++p) {
            z[p][0] = fmaf(h[p][4], w[ 4], fmaf(h[p][3], w[ 3], fmaf(h[p][2], w[ 2], fmaf(h[p][1], w[ 1], fmaf(h[p][0], w[ 0], b0)))));
            z[p][1] = fmaf(h[p][4], w[ 9], fmaf(h[p][3], w[ 8], fmaf(h[p][2], w[ 7], fmaf(h[p][1], w[ 6], fmaf(h[p][0], w[ 5], b1)))));
            z[p][2] = fmaf(h[p][4], w[14], fmaf(h[p][3], w[13], fmaf(h[p][2], w[12], fmaf(h[p][1], w[11], fmaf(h[p][0], w[10], b2)))));
            z[p][3] = fmaf(h[p][4], w[19], fmaf(h[p][3], w[18], fmaf(h[p][2], w[17], fmaf(h[p][1], w[16], fmaf(h[p][0], w[15], b3)))));
            z[p][4] = fmaf(h[p][4], w[24], fmaf(h[p][3], w[23], fmaf(h[p][2], w[22], fmaf(h[p][1], w[21], fmaf(h[p][0], w[20], b4)))));
        }
#pragma unroll
        for (int p = 0; p < PTS; ++p) {
#pragma unroll
            for (int j = 0; j < SIREN_HID; ++j)
                h[p][j] = sinrev(z[p][j]);
        }
    }

    // final linear (plain units, no sine)
    float w0 = Wfin[0], w1 = Wfin[1], w2 = Wfin[2], w3 = Wfin[3], w4 = Wfin[4];
    float bb = bfin[0];
    float o[PTS];
#pragma unroll
    for (int p = 0; p < PTS; ++p)
        o[p] = fmaf(h[p][4], w4, fmaf(h[p][3], w3, fmaf(h[p][2], w2, fmaf(h[p][1], w1, fmaf(h[p][0], w0, bb)))));

    // contiguous 16B store of the 4 outputs
    float4* op4 = (float4*)(out + PTS * i);
    *op4 = make_float4(o[0], o[1], o[2], o[3]);

    // coords passthrough (second tuple element), 48B contiguous
    float4* oc4 = (float4*)(out + N + 3 * PTS * i);
    oc4[0] = q0; oc4[1] = q1; oc4[2] = q2;
}

extern "C" void kernel_launch(void* const* d_in, const int* in_sizes, int n_in,
                              void* d_out, int out_size, void* d_ws, size_t ws_size,
                              hipStream_t stream) {
    const float* coords = (const float*)d_in[0];
    const float* Wf     = (const float*)d_in[1];
    const float* bf     = (const float*)d_in[2];
    const float* Wh     = (const float*)d_in[3];
    const float* bh     = (const float*)d_in[4];
    const float* Wfin   = (const float*)d_in[5];
    const float* bfin   = (const float*)d_in[6];

    int N = in_sizes[0] / 3;
    float* out = (float*)d_out;
    float* ws = (float*)d_ws;

    hipLaunchKernelGGL(siren_prep, dim3(32), dim3(256), 0, stream, Wf, bf, Wh, bh, ws);

    int M = N / PTS;                     // 4 points per thread; N=524288 -> 131072
    dim3 block(256);
    dim3 grid((M + 255) / 256);
    hipLaunchKernelGGL(siren_fwd5, grid, block, 0, stream,
                       coords, ws, ws + SIREN_NLAYERS * 32, Wfin, bfin, out, N);
}